// Round 7
// baseline (156.926 us; speedup 1.0000x reference)
//
#include <hip/hip_runtime.h>

typedef unsigned short u16;
typedef unsigned int u32;
typedef __attribute__((ext_vector_type(8))) short bf16x8;
typedef __attribute__((ext_vector_type(4))) short bf16x4;
typedef __attribute__((ext_vector_type(4))) float f32x4;

#define MFMA16(a, b, c) __builtin_amdgcn_mfma_f32_16x16x32_bf16(a, b, c, 0, 0, 0)
// K=16 bf16 MFMA (gfx90a-lineage "_1k" builtin, valid on gfx950 per ISA §10).
#define MFMAK16(a, b, c) __builtin_amdgcn_mfma_f32_16x16x16bf16_1k(a, b, c, 0, 0, 0)

__device__ __forceinline__ float hw_exp2(float x) { return __builtin_amdgcn_exp2f(x); }

__device__ __forceinline__ u16 f2bf(float f) {
    union { float f; u32 i; } v; v.f = f;
    u32 x = v.i;
    return (u16)((x + 0x7FFFu + ((x >> 16) & 1u)) >> 16);
}

// HW packed f32->bf16 (RNE, same rounding as f2bf). No builtin on gfx950; T12 recipe.
__device__ __forceinline__ u32 cvt_pk_bf16(float lo, float hi) {
    u32 r;
    asm("v_cvt_pk_bf16_f32 %0, %1, %2" : "=v"(r) : "v"(lo), "v"(hi));
    return r;
}

// 8 fp32 -> bf16x8 in 4 HW instructions.
__device__ __forceinline__ bf16x8 pack8(float4 a, float4 b) {
    union { u32 u[4]; bf16x8 v; } r;
    r.u[0] = cvt_pk_bf16(a.x, a.y);
    r.u[1] = cvt_pk_bf16(a.z, a.w);
    r.u[2] = cvt_pk_bf16(b.x, b.y);
    r.u[3] = cvt_pk_bf16(b.z, b.w);
    return r.v;
}

// ---------------- kernel 1: qkv = bf16(x) @ bf16(w_qkv), inline conversion ----------------
__global__ __launch_bounds__(256) void k_gemm_qkv(const float* __restrict__ x,
                                                  const float* __restrict__ wqkv,
                                                  u16* __restrict__ qkv) {
    __shared__ __align__(16) u16 smem[16896];  // B-tile [64][264] (33 KB); epilogue reuses 8704
    const int tid = threadIdx.x;
    const int wave = tid >> 6, lane = tid & 63, quad = lane >> 4, ql = lane & 15;
    const int by = blockIdx.y;
    const int mbase = blockIdx.x * 128 + (wave & 1) * 64;
    const float QSCALE2 = 0.2550566756538019f;  // 32^-0.5 * log2(e)

    // stage B slice: wqkv cols [by*64, by*64+64), all 256 k, transposed to [n][k] bf16
    {
        const int c4 = (tid & 15) * 4;
        const float sc = (by < 4) ? QSCALE2 : 1.0f;  // Q = first 256 out-cols (by 0..3)
        for (int kk = tid >> 4; kk < 256; kk += 16) {
            float4 w4 = *(const float4*)(wqkv + (size_t)kk * 768 + by * 64 + c4);
            smem[(c4 + 0) * 264 + kk] = f2bf(w4.x * sc);
            smem[(c4 + 1) * 264 + kk] = f2bf(w4.y * sc);
            smem[(c4 + 2) * 264 + kk] = f2bf(w4.z * sc);
            smem[(c4 + 3) * 264 + kk] = f2bf(w4.w * sc);
        }
    }
    __syncthreads();

    const int nrow = (wave >> 1) * 32;  // n-local base of this wave
    f32x4 acc[4][2];
#pragma unroll
    for (int i = 0; i < 4; ++i)
#pragma unroll
        for (int j = 0; j < 2; ++j) acc[i][j] = (f32x4){0.f, 0.f, 0.f, 0.f};
#pragma unroll
    for (int ks = 0; ks < 8; ++ks) {
        bf16x8 af[4], bfm[2];
#pragma unroll
        for (int ms = 0; ms < 4; ++ms) {
            const float* ap = x + (size_t)(mbase + ms * 16 + ql) * 256 + ks * 32 + quad * 8;
            af[ms] = pack8(*(const float4*)ap, *(const float4*)(ap + 4));
        }
#pragma unroll
        for (int ns = 0; ns < 2; ++ns)
            bfm[ns] = *(const bf16x8*)&smem[(nrow + ns * 16 + ql) * 264 + ks * 32 + quad * 8];
#pragma unroll
        for (int ms = 0; ms < 4; ++ms)
#pragma unroll
            for (int ns = 0; ns < 2; ++ns)
                acc[ms][ns] = MFMA16(af[ms], bfm[ns], acc[ms][ns]);
    }
    __syncthreads();  // B-tile reads done before epilogue reuses smem

    u16* slds = smem;
    const int t = (by * 64) >> 8;  // 0=Q, 1=K, 2=V (uniform per block)
    if (t < 2) {
        const int rowb = (wave & 1) * 64, colb = (wave >> 1) * 32;
#pragma unroll
        for (int ms = 0; ms < 4; ++ms)
#pragma unroll
            for (int ns = 0; ns < 2; ++ns)
#pragma unroll
                for (int r = 0; r < 4; ++r)
                    slds[(rowb + ms * 16 + quad * 4 + r) * 68 + colb + ns * 16 + ql] =
                        f2bf(acc[ms][ns][r]);
        __syncthreads();
        u16* base = qkv + (size_t)t * 2097152;
#pragma unroll
        for (int p = 0; p < 8; ++p) {
            int c = p * 256 + tid;
            int row = c >> 4, ch = c & 15;
            uint2 w = *(const uint2*)&slds[row * 68 + ch * 4];
            int n = blockIdx.x * 128 + row;
            int col = by * 64 + ch * 4;
            int h = (col & 255) >> 5, d = col & 31;
            *(uint2*)(base + ((size_t)((n >> 11) * 8 + h) * 2048 + (n & 2047)) * 32 + d) = w;
        }
    } else {
        const int hl = wave >> 1, nb = (wave & 1) * 64;
#pragma unroll
        for (int ms = 0; ms < 4; ++ms)
#pragma unroll
            for (int ns = 0; ns < 2; ++ns) {
                uint2 pp;
                pp.x = cvt_pk_bf16(acc[ms][ns][0], acc[ms][ns][1]);
                pp.y = cvt_pk_bf16(acc[ms][ns][2], acc[ms][ns][3]);
                *(uint2*)&slds[(hl * 32 + ns * 16 + ql) * 136 + nb + ms * 16 + quad * 4] = pp;
            }
        __syncthreads();
        u16* vbase = qkv + (size_t)2 * 2097152;
#pragma unroll
        for (int p = 0; p < 4; ++p) {
            int c = p * 256 + tid;
            int row = c >> 4, ch = c & 15;
            bf16x8 w = *(const bf16x8*)&slds[row * 136 + ch * 8];
            int n0 = blockIdx.x * 128 + ch * 8;
            int h = (by & 3) * 2 + (row >> 5), d = row & 31;
            *(bf16x8*)(vbase + (size_t)((n0 >> 11) * 8 + h) * 65536 +
                       (size_t)d * 2048 + (n0 & 2047)) = w;
        }
    }
}

// ---------------- kernel 2: flash attention, QBLK=64, 4 blocks/CU --------------
// ROUND 7: latency-hypothesis test. DS/VALU/bias cuts were all null (r0/r5/r6), so
// attn is modeled latency-bound at 2 blocks/CU (2 waves/SIMD -- minimal overlap).
// QBLK 128->64: grid 1024 (bh = bid&31, qt = bid>>5 in 0..31), per-wave state halved
// (1 qh: qf/oT0/oT1/oL single), __launch_bounds__(256,4) caps VGPR<=128 ->
// 4 blocks/CU = 4 waves/SIMD. Total MFMA/exp work unchanged; DS/VMEM double
// (proven ~free); K/V stream stays L2-hot. Bias back in LDS (r6's global variant
// regressed -- reverted).
__global__ __launch_bounds__(256, 4) void k_attn(const u16* __restrict__ q,
                                                 const u16* __restrict__ k,
                                                 const u16* __restrict__ vT,
                                                 const float* __restrict__ table,
                                                 u16* __restrict__ att) {
    __shared__ __align__(16) u16 kbuf[2][2][2048];  // [buf][tile][swizzled 64x32]
    __shared__ __align__(16) u16 vbuf[2][2][2048];  // [buf][tile][32 d][64 n swizzled 8-chunks]
    __shared__ float tbl2[2176];
    const int tid = threadIdx.x;
    const int bh = blockIdx.x & 31, qt = blockIdx.x >> 5;  // qt in 0..31
    const int wave = tid >> 6, lane = tid & 63, quad = lane >> 4, ql = lane & 15;
    const float LOG2E = 1.4426950408889634f;

    const u16* kbh = k + (size_t)bh * 65536;
    const u16* vbh = vT + (size_t)bh * 65536;  // [32 d][2048 n]

    // DMA lane->global maps (LDS side forced contiguous: base + lane*16B).
    const int krow = wave * 16 + (lane >> 2);
    const u16* kg = kbh + krow * 32 + ((((lane & 3) ^ ((lane >> 3) & 3))) << 3);
    const int vd = wave * 8 + (lane >> 3);
    const u16* vg = vbh + (size_t)vd * 2048 + (((lane & 7) ^ (vd & 7)) << 3);

#define GLDS(SRC, DST) __builtin_amdgcn_global_load_lds(                         \
        (const __attribute__((address_space(1))) void*)(SRC),                    \
        (__attribute__((address_space(3))) void*)(DST), 16, 0, 0)
#define DMA(BUF, PAIR) do {                                                      \
    GLDS(kg + (PAIR) * 4096,        &kbuf[BUF][0][wave * 512]);                  \
    GLDS(kg + (PAIR) * 4096 + 2048, &kbuf[BUF][1][wave * 512]);                  \
    GLDS(vg + (PAIR) * 128,         &vbuf[BUF][0][wave * 512]);                  \
    GLDS(vg + (PAIR) * 128 + 64,    &vbuf[BUF][1][wave * 512]);                  \
} while (0)

    DMA(0, 0);  // pair 0 in flight during bias staging

    // bias window for QBLK=64: local idx = q - kv + 2047 - qt*64 in [0, 2111]
    const float4* tg = (const float4*)(table + qt * 64);
    for (int i = tid; i < 528; i += 256) {
        float4 t = tg[i];
        t.x *= LOG2E; t.y *= LOG2E; t.z *= LOG2E; t.w *= LOG2E;
        ((float4*)tbl2)[i] = t;
    }

    const int qr0 = qt * 64 + wave * 16 + ql;
    bf16x8 qf = *(const bf16x8*)(q + ((size_t)bh * 2048 + qr0) * 32 + quad * 8);
    const int bloc0 = wave * 16 + ql + 2047 - quad * 4;
    const int kro = ((quad ^ ((ql >> 1) & 3)) << 3);    // K read swizzle offset

    bf16x4 ones4;
#pragma unroll
    for (int i = 0; i < 4; ++i) ones4[i] = (short)0x3F80;  // bf16 1.0

    f32x4 oT0 = {0.f, 0.f, 0.f, 0.f};
    f32x4 oT1 = {0.f, 0.f, 0.f, 0.f};
    f32x4 oL  = {0.f, 0.f, 0.f, 0.f};

    __syncthreads();  // bias + pair 0 ready

    for (int pr = 0; pr < 16; ++pr) {
        const int buf = pr & 1;

        // bias C-fragments (1 qh -> 4 groups of 4): bc[t][3-j][r] = bias at
        // (q=ql-col, kv = kt*64 + j*16 + quad*4 + r), matching S^T C/D layout.
        f32x4 bc[2][4];
#pragma unroll
        for (int t = 0; t < 2; ++t) {
            const int bkt = bloc0 - (pr * 2 + t) * 64;
#pragma unroll
            for (int g = 0; g < 4; ++g) {
                const int b0 = bkt + 16 * g - 51;
                bc[t][g] = (f32x4){tbl2[b0 + 3], tbl2[b0 + 2], tbl2[b0 + 1], tbl2[b0 + 0]};
            }
        }
        __builtin_amdgcn_sched_barrier(0);  // bias reads issue before the DMA

        if (pr < 15) DMA(buf ^ 1, pr + 1);  // lands during this 2-tile body

#pragma unroll
        for (int t = 0; t < 2; ++t) {
            const u16* kb = &kbuf[buf][t][0];
            const u16* vb = &vbuf[buf][t][0];
            bf16x8 kf[4];
            bf16x4 va[2][4];  // [d-tile][j]: A-frag of V^T, k = quad*4 + reg
#pragma unroll
            for (int j = 0; j < 4; ++j)
                kf[j] = *(const bf16x8*)(kb + (j * 16 + ql) * 32 + kro);
#pragma unroll
            for (int dt = 0; dt < 2; ++dt)
#pragma unroll
                for (int j = 0; j < 4; ++j) {
                    int nloc = j * 16 + quad * 4;           // n-local base of this A-frag
                    int slot = (nloc >> 3) ^ (ql & 7);      // V chunk swizzle
                    va[dt][j] = *(const bf16x4*)(vb + (dt * 16 + ql) * 64 +
                                                 slot * 8 + (nloc & 7));
                }

            __builtin_amdgcn_s_setprio(1);  // T5: favor MFMA-issuing wave
            f32x4 s[4];
#pragma unroll
            for (int j = 0; j < 4; ++j)
                s[j] = MFMA16(kf[j], qf, bc[t][3 - j]);  // bias via C
#pragma unroll
            for (int j = 0; j < 4; ++j)
#pragma unroll
                for (int r = 0; r < 4; ++r)
                    s[j][r] = hw_exp2(s[j][r]);
#pragma unroll
            for (int j = 0; j < 4; ++j) {
                union { u32 u[2]; bf16x4 v; } pj;
                pj.u[0] = __builtin_amdgcn_perm(__float_as_uint(s[j][1]),
                                                __float_as_uint(s[j][0]), 0x07060302u);
                pj.u[1] = __builtin_amdgcn_perm(__float_as_uint(s[j][3]),
                                                __float_as_uint(s[j][2]), 0x07060302u);
                oT0 = MFMAK16(va[0][j], pj.v, oT0);
                oT1 = MFMAK16(va[1][j], pj.v, oT1);
                oL  = MFMAK16(ones4, pj.v, oL);
            }
            __builtin_amdgcn_s_setprio(0);
        }
        __syncthreads();  // buf reads done; next DMA drained
    }
#undef DMA
#undef GLDS

    // epilogue: every oL reg holds l for q-col=ql; no shuffles needed
    {
        float inv = 1.0f / oL[0];
        size_t base = ((size_t)bh * 2048 + qr0) * 32;
#pragma unroll
        for (int dt = 0; dt < 2; ++dt) {
            const f32x4& o = dt ? oT1 : oT0;
            uint2 pp;
            pp.x = cvt_pk_bf16(o[0] * inv, o[1] * inv);
            pp.y = cvt_pk_bf16(o[2] * inv, o[3] * inv);
            *(uint2*)(att + base + dt * 16 + quad * 4) = pp;
        }
    }
}

// ---------------- kernel 3: out = att @ bf16(w_out) + b_out -> fp32 d_out ----------------
__global__ __launch_bounds__(256) void k_gemm_out(const u16* __restrict__ attq,
                                                  const float* __restrict__ wout,
                                                  const float* __restrict__ bout,
                                                  float* __restrict__ out) {
    __shared__ __align__(16) u16 bs[16896];  // [64][264] bf16 B-tile
    const int tid = threadIdx.x;
    const int wave = tid >> 6, lane = tid & 63, quad = lane >> 4, ql = lane & 15;
    const int by = blockIdx.y;
    const int mbase = blockIdx.x * 128 + (wave & 1) * 64;

    {
        const int c4 = (tid & 15) * 4;
        for (int kk = tid >> 4; kk < 256; kk += 16) {
            float4 w4 = *(const float4*)(wout + (size_t)kk * 256 + by * 64 + c4);
            bs[(c4 + 0) * 264 + kk] = f2bf(w4.x);
            bs[(c4 + 1) * 264 + kk] = f2bf(w4.y);
            bs[(c4 + 2) * 264 + kk] = f2bf(w4.z);
            bs[(c4 + 3) * 264 + kk] = f2bf(w4.w);
        }
    }
    __syncthreads();

    const int nrow = (wave >> 1) * 32;
    f32x4 acc[4][2];
#pragma unroll
    for (int i = 0; i < 4; ++i)
#pragma unroll
        for (int j = 0; j < 2; ++j) acc[i][j] = (f32x4){0.f, 0.f, 0.f, 0.f};
#pragma unroll
    for (int ks = 0; ks < 8; ++ks) {
        bf16x8 af[4], bfm[2];
#pragma unroll
        for (int ms = 0; ms < 4; ++ms) {
            int row = mbase + ms * 16 + ql;
            af[ms] = *(const bf16x8*)(attq +
                ((size_t)((row >> 11) * 8 + ks) * 2048 + (row & 2047)) * 32 + quad * 8);
        }
#pragma unroll
        for (int ns = 0; ns < 2; ++ns)
            bfm[ns] = *(const bf16x8*)&bs[(nrow + ns * 16 + ql) * 264 + ks * 32 + quad * 8];
#pragma unroll
        for (int ms = 0; ms < 4; ++ms)
#pragma unroll
            for (int ns = 0; ns < 2; ++ns)
                acc[ms][ns] = MFMA16(af[ms], bfm[ns], acc[ms][ns]);
    }
#pragma unroll
    for (int ms = 0; ms < 4; ++ms)
#pragma unroll
        for (int ns = 0; ns < 2; ++ns)
#pragma unroll
            for (int r = 0; r < 4; ++r) {
                int Mrow = mbase + ms * 16 + quad * 4 + r;
                int col = by * 64 + (wave >> 1) * 32 + ns * 16 + ql;
                out[(size_t)Mrow * 256 + col] = acc[ms][ns][r] + bout[col];
            }
}

extern "C" void kernel_launch(void* const* d_in, const int* in_sizes, int n_in,
                              void* d_out, int out_size, void* d_ws, size_t ws_size,
                              hipStream_t stream) {
    const float* x    = (const float*)d_in[0];  // [4,2048,256] fp32
    const float* wqkv = (const float*)d_in[1];  // [256,768] fp32
    const float* btab = (const float*)d_in[2];  // [16384,1] fp32
    const float* wout = (const float*)d_in[3];  // [256,256] fp32
    const float* bout = (const float*)d_in[4];  // [256] fp32
    // d_in[5] relative_pos is Toeplitz (i - j + 2047) -- computed analytically, not read.
    float* out = (float*)d_out;                 // [4,2048,256] fp32

    // ws layout: qkv only -- Q [B*H][N][D] | K [B*H][N][D] | V^T [B*H][D][N], bf16
    if (ws_size < (size_t)12582912) return;
    u16* qkv = (u16*)d_ws;

    hipLaunchKernelGGL(k_gemm_qkv, dim3(64, 12), dim3(256), 0, stream, x, wqkv, qkv);
    // k_attn writes its output (bf16, [B*H][N][D]) back into the Q third of qkv.
    hipLaunchKernelGGL(k_attn, dim3(1024), dim3(256), 0, stream,
                       qkv, qkv + 2097152, qkv + 2 * 2097152, btab, qkv);
    hipLaunchKernelGGL(k_gemm_out, dim3(64, 4), dim3(256), 0, stream, qkv, wout, bout, out);
}

// Round 8
// 143.415 us; speedup vs baseline: 1.0942x; 1.0942x over previous
//
#include <hip/hip_runtime.h>

typedef unsigned short u16;
typedef unsigned int u32;
typedef __attribute__((ext_vector_type(8))) short bf16x8;
typedef __attribute__((ext_vector_type(4))) short bf16x4;
typedef __attribute__((ext_vector_type(4))) float f32x4;

#define MFMA16(a, b, c) __builtin_amdgcn_mfma_f32_16x16x32_bf16(a, b, c, 0, 0, 0)
// K=16 bf16 MFMA (gfx90a-lineage "_1k" builtin, valid on gfx950 per ISA §10).
#define MFMAK16(a, b, c) __builtin_amdgcn_mfma_f32_16x16x16bf16_1k(a, b, c, 0, 0, 0)

__device__ __forceinline__ float hw_exp2(float x) { return __builtin_amdgcn_exp2f(x); }

__device__ __forceinline__ u16 f2bf(float f) {
    union { float f; u32 i; } v; v.f = f;
    u32 x = v.i;
    return (u16)((x + 0x7FFFu + ((x >> 16) & 1u)) >> 16);
}

// HW packed f32->bf16 (RNE, same rounding as f2bf). No builtin on gfx950; T12 recipe.
__device__ __forceinline__ u32 cvt_pk_bf16(float lo, float hi) {
    u32 r;
    asm("v_cvt_pk_bf16_f32 %0, %1, %2" : "=v"(r) : "v"(lo), "v"(hi));
    return r;
}

// 8 fp32 -> bf16x8 in 4 HW instructions.
__device__ __forceinline__ bf16x8 pack8(float4 a, float4 b) {
    union { u32 u[4]; bf16x8 v; } r;
    r.u[0] = cvt_pk_bf16(a.x, a.y);
    r.u[1] = cvt_pk_bf16(a.z, a.w);
    r.u[2] = cvt_pk_bf16(b.x, b.y);
    r.u[3] = cvt_pk_bf16(b.z, b.w);
    return r.v;
}

// ---------------- kernel 1: qkv = bf16(x) @ bf16(w_qkv), inline conversion ----------------
__global__ __launch_bounds__(256) void k_gemm_qkv(const float* __restrict__ x,
                                                  const float* __restrict__ wqkv,
                                                  u16* __restrict__ qkv) {
    __shared__ __align__(16) u16 smem[16896];  // B-tile [64][264] (33 KB); epilogue reuses 8704
    const int tid = threadIdx.x;
    const int wave = tid >> 6, lane = tid & 63, quad = lane >> 4, ql = lane & 15;
    const int by = blockIdx.y;
    const int mbase = blockIdx.x * 128 + (wave & 1) * 64;
    const float QSCALE2 = 0.2550566756538019f;  // 32^-0.5 * log2(e)

    // stage B slice: wqkv cols [by*64, by*64+64), all 256 k, transposed to [n][k] bf16
    {
        const int c4 = (tid & 15) * 4;
        const float sc = (by < 4) ? QSCALE2 : 1.0f;  // Q = first 256 out-cols (by 0..3)
        for (int kk = tid >> 4; kk < 256; kk += 16) {
            float4 w4 = *(const float4*)(wqkv + (size_t)kk * 768 + by * 64 + c4);
            smem[(c4 + 0) * 264 + kk] = f2bf(w4.x * sc);
            smem[(c4 + 1) * 264 + kk] = f2bf(w4.y * sc);
            smem[(c4 + 2) * 264 + kk] = f2bf(w4.z * sc);
            smem[(c4 + 3) * 264 + kk] = f2bf(w4.w * sc);
        }
    }
    __syncthreads();

    const int nrow = (wave >> 1) * 32;  // n-local base of this wave
    f32x4 acc[4][2];
#pragma unroll
    for (int i = 0; i < 4; ++i)
#pragma unroll
        for (int j = 0; j < 2; ++j) acc[i][j] = (f32x4){0.f, 0.f, 0.f, 0.f};
#pragma unroll
    for (int ks = 0; ks < 8; ++ks) {
        bf16x8 af[4], bfm[2];
#pragma unroll
        for (int ms = 0; ms < 4; ++ms) {
            const float* ap = x + (size_t)(mbase + ms * 16 + ql) * 256 + ks * 32 + quad * 8;
            af[ms] = pack8(*(const float4*)ap, *(const float4*)(ap + 4));
        }
#pragma unroll
        for (int ns = 0; ns < 2; ++ns)
            bfm[ns] = *(const bf16x8*)&smem[(nrow + ns * 16 + ql) * 264 + ks * 32 + quad * 8];
#pragma unroll
        for (int ms = 0; ms < 4; ++ms)
#pragma unroll
            for (int ns = 0; ns < 2; ++ns)
                acc[ms][ns] = MFMA16(af[ms], bfm[ns], acc[ms][ns]);
    }
    __syncthreads();  // B-tile reads done before epilogue reuses smem

    u16* slds = smem;
    const int t = (by * 64) >> 8;  // 0=Q, 1=K, 2=V (uniform per block)
    if (t < 2) {
        const int rowb = (wave & 1) * 64, colb = (wave >> 1) * 32;
#pragma unroll
        for (int ms = 0; ms < 4; ++ms)
#pragma unroll
            for (int ns = 0; ns < 2; ++ns)
#pragma unroll
                for (int r = 0; r < 4; ++r)
                    slds[(rowb + ms * 16 + quad * 4 + r) * 68 + colb + ns * 16 + ql] =
                        f2bf(acc[ms][ns][r]);
        __syncthreads();
        u16* base = qkv + (size_t)t * 2097152;
#pragma unroll
        for (int p = 0; p < 8; ++p) {
            int c = p * 256 + tid;
            int row = c >> 4, ch = c & 15;
            uint2 w = *(const uint2*)&slds[row * 68 + ch * 4];
            int n = blockIdx.x * 128 + row;
            int col = by * 64 + ch * 4;
            int h = (col & 255) >> 5, d = col & 31;
            *(uint2*)(base + ((size_t)((n >> 11) * 8 + h) * 2048 + (n & 2047)) * 32 + d) = w;
        }
    } else {
        const int hl = wave >> 1, nb = (wave & 1) * 64;
#pragma unroll
        for (int ms = 0; ms < 4; ++ms)
#pragma unroll
            for (int ns = 0; ns < 2; ++ns) {
                uint2 pp;
                pp.x = cvt_pk_bf16(acc[ms][ns][0], acc[ms][ns][1]);
                pp.y = cvt_pk_bf16(acc[ms][ns][2], acc[ms][ns][3]);
                *(uint2*)&slds[(hl * 32 + ns * 16 + ql) * 136 + nb + ms * 16 + quad * 4] = pp;
            }
        __syncthreads();
        u16* vbase = qkv + (size_t)2 * 2097152;
#pragma unroll
        for (int p = 0; p < 4; ++p) {
            int c = p * 256 + tid;
            int row = c >> 4, ch = c & 15;
            bf16x8 w = *(const bf16x8*)&slds[row * 136 + ch * 8];
            int n0 = blockIdx.x * 128 + ch * 8;
            int h = (by & 3) * 2 + (row >> 5), d = row & 31;
            *(bf16x8*)(vbase + (size_t)((n0 >> 11) * 8 + h) * 65536 +
                       (size_t)d * 2048 + (n0 & 2047)) = w;
        }
    }
}

// ---------------- kernel 2: flash attention, QBLK=128, triple-buffer + counted vmcnt ----
// ROUND 8: r7 counters showed attn latency-bound (no pipe >45%, occ 20%). QBLK back to
// 128 (r7's 64 doubled per-tile costs: +12us). NEW: the per-pr __syncthreads forced
// vmcnt(0) -- a full DMA drain, uncoverable at 2 blocks/CU. Replaced by T3/T4:
// 3 K/V buffers, raw s_barrier + s_waitcnt vmcnt(4) so the NEXT pair's 4 loads stay
// in flight across the barrier; pair pr+2 issued right after the barrier.
// No in-loop ds_write => raw barrier needs no lgkmcnt drain. sched_barrier(0) fences
// per rule #18. LDS 56.5 KB -> still 2 blocks/CU.
__global__ __launch_bounds__(256, 2) void k_attn(const u16* __restrict__ q,
                                                 const u16* __restrict__ k,
                                                 const u16* __restrict__ vT,
                                                 const float* __restrict__ table,
                                                 u16* __restrict__ att) {
    __shared__ __align__(16) u16 kbuf[3][2][2048];  // [buf][tile][swizzled 64x32]
    __shared__ __align__(16) u16 vbuf[3][2][2048];  // [buf][tile][32 d][64 n swizzled 8-chunks]
    __shared__ float tbl2[2176];
    const int tid = threadIdx.x;
    const int bh = blockIdx.x & 31, qt = blockIdx.x >> 5;
    const int wave = tid >> 6, lane = tid & 63, quad = lane >> 4, ql = lane & 15;
    const float LOG2E = 1.4426950408889634f;

    const u16* kbh = k + (size_t)bh * 65536;
    const u16* vbh = vT + (size_t)bh * 65536;  // [32 d][2048 n]

    // DMA lane->global maps (LDS side forced contiguous: base + lane*16B).
    const int krow = wave * 16 + (lane >> 2);
    const u16* kg = kbh + krow * 32 + ((((lane & 3) ^ ((lane >> 3) & 3))) << 3);
    const int vd = wave * 8 + (lane >> 3);
    const u16* vg = vbh + (size_t)vd * 2048 + (((lane & 7) ^ (vd & 7)) << 3);

#define GLDS(SRC, DST) __builtin_amdgcn_global_load_lds(                         \
        (const __attribute__((address_space(1))) void*)(SRC),                    \
        (__attribute__((address_space(3))) void*)(DST), 16, 0, 0)
#define DMA(BUF, PAIR) do {                                                      \
    GLDS(kg + (PAIR) * 4096,        &kbuf[BUF][0][wave * 512]);                  \
    GLDS(kg + (PAIR) * 4096 + 2048, &kbuf[BUF][1][wave * 512]);                  \
    GLDS(vg + (PAIR) * 128,         &vbuf[BUF][0][wave * 512]);                  \
    GLDS(vg + (PAIR) * 128 + 64,    &vbuf[BUF][1][wave * 512]);                  \
} while (0)

    DMA(0, 0);  // pairs 0 and 1 in flight during bias staging
    DMA(1, 1);

    // bias window: idx = q - kv + 2047 - qt*128 in [0, 2174]
    const float4* tg = (const float4*)(table + qt * 128);
    for (int i = tid; i < 544; i += 256) {
        float4 t = tg[i];
        t.x *= LOG2E; t.y *= LOG2E; t.z *= LOG2E; t.w *= LOG2E;
        ((float4*)tbl2)[i] = t;
    }

    const int qr0 = qt * 128 + wave * 32 + ql;
    bf16x8 qf[2];
    qf[0] = *(const bf16x8*)(q + ((size_t)bh * 2048 + qr0) * 32 + quad * 8);
    qf[1] = *(const bf16x8*)(q + ((size_t)bh * 2048 + qr0 + 16) * 32 + quad * 8);
    const int bloc0 = wave * 32 + ql + 2047 - quad * 4;
    const int kro = ((quad ^ ((ql >> 1) & 3)) << 3);    // K read swizzle offset

    bf16x4 ones4;
#pragma unroll
    for (int i = 0; i < 4; ++i) ones4[i] = (short)0x3F80;  // bf16 1.0

    f32x4 oT0[2], oT1[2], oL[2];
#pragma unroll
    for (int qh = 0; qh < 2; ++qh) {
        oT0[qh] = (f32x4){0.f, 0.f, 0.f, 0.f};
        oT1[qh] = (f32x4){0.f, 0.f, 0.f, 0.f};
        oL[qh]  = (f32x4){0.f, 0.f, 0.f, 0.f};
    }

    __syncthreads();  // bias + pairs 0,1 landed; vmcnt drained to 0 here

    int buf = 0, nxt = 2;  // buffer holding pair pr; buffer for pair pr+2
    for (int pr = 0; pr < 16; ++pr) {
        // T4 counted wait: pair pr's 4 loads done, pair pr+1's 4 stay in flight.
        // Steady state: enter with 8 outstanding -> wait to 4 -> issue to 8.
        if (pr < 14) asm volatile("s_waitcnt vmcnt(4)" ::: "memory");
        else         asm volatile("s_waitcnt vmcnt(0)" ::: "memory");
        __builtin_amdgcn_sched_barrier(0);
        __builtin_amdgcn_s_barrier();       // raw: no compiler vmcnt(0) drain
        __builtin_amdgcn_sched_barrier(0);

        if (pr <= 13) DMA(nxt, pr + 2);     // overwrites buf all waves left at pr-1

        // bias C-fragments for both tiles of this pair, from the LDS window.
        // bc[t][g][r] matches the S^T C/D layout (col=ql, row=quad*4+r).
        f32x4 bc[2][5];
#pragma unroll
        for (int t = 0; t < 2; ++t) {
            const int bkt = bloc0 - (pr * 2 + t) * 64;
#pragma unroll
            for (int g = 0; g < 5; ++g) {
                const int b0 = bkt + 16 * g - 51;
                bc[t][g] = (f32x4){tbl2[b0 + 3], tbl2[b0 + 2], tbl2[b0 + 1], tbl2[b0 + 0]};
            }
        }

#pragma unroll
        for (int t = 0; t < 2; ++t) {
            const u16* kb = &kbuf[buf][t][0];
            const u16* vb = &vbuf[buf][t][0];
            bf16x8 kf[4];
            bf16x4 va[2][4];  // [d-tile][j]: A-frag of V^T, k = quad*4 + reg
#pragma unroll
            for (int j = 0; j < 4; ++j)
                kf[j] = *(const bf16x8*)(kb + (j * 16 + ql) * 32 + kro);
#pragma unroll
            for (int dt = 0; dt < 2; ++dt)
#pragma unroll
                for (int j = 0; j < 4; ++j) {
                    int nloc = j * 16 + quad * 4;           // n-local base of this A-frag
                    int slot = (nloc >> 3) ^ (ql & 7);      // V chunk swizzle
                    va[dt][j] = *(const bf16x4*)(vb + (dt * 16 + ql) * 64 +
                                                 slot * 8 + (nloc & 7));
                }

#pragma unroll
            for (int qh = 0; qh < 2; ++qh) {
                __builtin_amdgcn_s_setprio(1);  // T5: favor MFMA-issuing wave
                f32x4 s[4];
#pragma unroll
                for (int j = 0; j < 4; ++j)
                    s[j] = MFMA16(kf[j], qf[qh], bc[t][qh + 3 - j]);  // bias via C
#pragma unroll
                for (int j = 0; j < 4; ++j)
#pragma unroll
                    for (int r = 0; r < 4; ++r)
                        s[j][r] = hw_exp2(s[j][r]);
#pragma unroll
                for (int j = 0; j < 4; ++j) {
                    union { u32 u[2]; bf16x4 v; } pj;
                    pj.u[0] = __builtin_amdgcn_perm(__float_as_uint(s[j][1]),
                                                    __float_as_uint(s[j][0]), 0x07060302u);
                    pj.u[1] = __builtin_amdgcn_perm(__float_as_uint(s[j][3]),
                                                    __float_as_uint(s[j][2]), 0x07060302u);
                    oT0[qh] = MFMAK16(va[0][j], pj.v, oT0[qh]);
                    oT1[qh] = MFMAK16(va[1][j], pj.v, oT1[qh]);
                    oL[qh]  = MFMAK16(ones4, pj.v, oL[qh]);
                }
                __builtin_amdgcn_s_setprio(0);
            }
        }
        buf = (buf == 2) ? 0 : buf + 1;
        nxt = (nxt == 2) ? 0 : nxt + 1;
    }
#undef DMA
#undef GLDS

    // epilogue: every oL reg holds l for q-col=ql; no shuffles needed
#pragma unroll
    for (int qh = 0; qh < 2; ++qh) {
        float inv = 1.0f / oL[qh][0];
        size_t base = ((size_t)bh * 2048 + qr0 + qh * 16) * 32;
#pragma unroll
        for (int dt = 0; dt < 2; ++dt) {
            const f32x4& o = dt ? oT1[qh] : oT0[qh];
            uint2 pp;
            pp.x = cvt_pk_bf16(o[0] * inv, o[1] * inv);
            pp.y = cvt_pk_bf16(o[2] * inv, o[3] * inv);
            *(uint2*)(att + base + dt * 16 + quad * 4) = pp;
        }
    }
}

// ---------------- kernel 3: out = att @ bf16(w_out) + b_out -> fp32 d_out ----------------
__global__ __launch_bounds__(256) void k_gemm_out(const u16* __restrict__ attq,
                                                  const float* __restrict__ wout,
                                                  const float* __restrict__ bout,
                                                  float* __restrict__ out) {
    __shared__ __align__(16) u16 bs[16896];  // [64][264] bf16 B-tile
    const int tid = threadIdx.x;
    const int wave = tid >> 6, lane = tid & 63, quad = lane >> 4, ql = lane & 15;
    const int by = blockIdx.y;
    const int mbase = blockIdx.x * 128 + (wave & 1) * 64;

    {
        const int c4 = (tid & 15) * 4;
        for (int kk = tid >> 4; kk < 256; kk += 16) {
            float4 w4 = *(const float4*)(wout + (size_t)kk * 256 + by * 64 + c4);
            bs[(c4 + 0) * 264 + kk] = f2bf(w4.x);
            bs[(c4 + 1) * 264 + kk] = f2bf(w4.y);
            bs[(c4 + 2) * 264 + kk] = f2bf(w4.z);
            bs[(c4 + 3) * 264 + kk] = f2bf(w4.w);
        }
    }
    __syncthreads();

    const int nrow = (wave >> 1) * 32;
    f32x4 acc[4][2];
#pragma unroll
    for (int i = 0; i < 4; ++i)
#pragma unroll
        for (int j = 0; j < 2; ++j) acc[i][j] = (f32x4){0.f, 0.f, 0.f, 0.f};
#pragma unroll
    for (int ks = 0; ks < 8; ++ks) {
        bf16x8 af[4], bfm[2];
#pragma unroll
        for (int ms = 0; ms < 4; ++ms) {
            int row = mbase + ms * 16 + ql;
            af[ms] = *(const bf16x8*)(attq +
                ((size_t)((row >> 11) * 8 + ks) * 2048 + (row & 2047)) * 32 + quad * 8);
        }
#pragma unroll
        for (int ns = 0; ns < 2; ++ns)
            bfm[ns] = *(const bf16x8*)&bs[(nrow + ns * 16 + ql) * 264 + ks * 32 + quad * 8];
#pragma unroll
        for (int ms = 0; ms < 4; ++ms)
#pragma unroll
            for (int ns = 0; ns < 2; ++ns)
                acc[ms][ns] = MFMA16(af[ms], bfm[ns], acc[ms][ns]);
    }
#pragma unroll
    for (int ms = 0; ms < 4; ++ms)
#pragma unroll
        for (int ns = 0; ns < 2; ++ns)
#pragma unroll
            for (int r = 0; r < 4; ++r) {
                int Mrow = mbase + ms * 16 + quad * 4 + r;
                int col = by * 64 + (wave >> 1) * 32 + ns * 16 + ql;
                out[(size_t)Mrow * 256 + col] = acc[ms][ns][r] + bout[col];
            }
}

extern "C" void kernel_launch(void* const* d_in, const int* in_sizes, int n_in,
                              void* d_out, int out_size, void* d_ws, size_t ws_size,
                              hipStream_t stream) {
    const float* x    = (const float*)d_in[0];  // [4,2048,256] fp32
    const float* wqkv = (const float*)d_in[1];  // [256,768] fp32
    const float* btab = (const float*)d_in[2];  // [16384,1] fp32
    const float* wout = (const float*)d_in[3];  // [256,256] fp32
    const float* bout = (const float*)d_in[4];  // [256] fp32
    // d_in[5] relative_pos is Toeplitz (i - j + 2047) -- computed analytically, not read.
    float* out = (float*)d_out;                 // [4,2048,256] fp32

    // ws layout: qkv only -- Q [B*H][N][D] | K [B*H][N][D] | V^T [B*H][D][N], bf16
    if (ws_size < (size_t)12582912) return;
    u16* qkv = (u16*)d_ws;

    hipLaunchKernelGGL(k_gemm_qkv, dim3(64, 12), dim3(256), 0, stream, x, wqkv, qkv);
    // k_attn writes its output (bf16, [B*H][N][D]) back into the Q third of qkv.
    hipLaunchKernelGGL(k_attn, dim3(512), dim3(256), 0, stream,
                       qkv, qkv + 2097152, qkv + 2 * 2097152, btab, qkv);
    hipLaunchKernelGGL(k_gemm_out, dim3(64, 4), dim3(256), 0, stream, qkv, wout, bout, out);
}